// Round 3
// baseline (130.220 us; speedup 1.0000x reference)
//
#include <hip/hip_runtime.h>
#include <stdint.h>

// buildProposalTargetLayer — exact JAX replication (partitionable threefry).
// Pipeline:
//   k_zero    : zero bucket counts + nfg/nbg
//   k_assign  : IoU max/argmax (2 rois/thread, float4 LDS), masks, keys, histogram
//   k_scan    : per-(b,set) exclusive scan of 8192 buckets (in-place) + cursors
//   k_scatter : scatter candidate composites into bucket ranges
//   k_bsort   : insertion sort per bucket (avg ~2.5 elems)
//   k_sample  : per-slot sampling + bbox target encoding -> d_out

typedef uint32_t u32;
typedef uint64_t u64;

constexpr int B    = 16;
constexpr int R    = 20000;
constexpr int G    = 100;
constexpr int N    = R + G;    // 20100
constexpr int S    = 512;
constexpr int KFG  = 128;
constexpr int NBKT = 8192;     // key>>10 buckets (23-bit keys)
constexpr u32 SENT = 0xFFFFFFFFu;
constexpr int TPB  = 256;      // k_assign block size
constexpr int RPT  = 2;        // rois per thread

// ---------------- threefry2x32 (20 rounds) ----------------
__device__ __forceinline__ void tf2x32(u32 k0, u32 k1, u32 x0, u32 x1,
                                       u32& o0, u32& o1) {
  u32 ks2 = k0 ^ k1 ^ 0x1BD11BDAu;
#define TFR(r) { x0 += x1; x1 = (x1 << (r)) | (x1 >> (32 - (r))); x1 ^= x0; }
  x0 += k0; x1 += k1;
  TFR(13) TFR(15) TFR(26) TFR(6)
  x0 += k1;  x1 += ks2 + 1u;
  TFR(17) TFR(29) TFR(16) TFR(24)
  x0 += ks2; x1 += k0 + 2u;
  TFR(13) TFR(15) TFR(26) TFR(6)
  x0 += k0;  x1 += k1 + 3u;
  TFR(17) TFR(29) TFR(16) TFR(24)
  x0 += k1;  x1 += ks2 + 4u;
  TFR(13) TFR(15) TFR(26) TFR(6)
  x0 += ks2; x1 += k0 + 5u;
#undef TFR
  o0 = x0; o1 = x1;
}

__device__ __forceinline__ void batch_key(int b, u32& kb0, u32& kb1) {
  tf2x32(0u, 42u, 0u, (u32)b, kb0, kb1);
}
__device__ __forceinline__ void sub_key(u32 kb0, u32 kb1, int j, u32& k0, u32& k1) {
  tf2x32(kb0, kb1, 0u, (u32)j, k0, k1);
}
__device__ __forceinline__ u32 rand_bits(u32 k0, u32 k1, int i) {
  u32 b0, b1;
  tf2x32(k0, k1, 0u, (u32)i, b0, b1);
  return b0 ^ b1;
}
__device__ __forceinline__ float bits_to_uniform(u32 bits) {
  return __uint_as_float((bits >> 9) | 0x3f800000u) - 1.0f;
}

// ---------------- kernels ----------------
__global__ void k_zero(u32* __restrict__ cnt, int* nfg, int* nbg) {
  const int total = B * 2 * NBKT;
  for (int i = blockIdx.x * blockDim.x + threadIdx.x; i < total;
       i += gridDim.x * blockDim.x)
    cnt[i] = 0;
  int t = blockIdx.x * blockDim.x + threadIdx.x;
  if (t < B) { nfg[t] = 0; nbg[t] = 0; }
}

__global__ __launch_bounds__(TPB) void
k_assign(const float* __restrict__ rois, const float* __restrict__ gts,
         u32* __restrict__ fgkey, u32* __restrict__ bgkey,
         int* __restrict__ gasn, u32* __restrict__ cnt,
         int* nfg, int* nbg) {
#pragma clang fp contract(off)
  __shared__ float4 gbox[G];
  __shared__ float garea[G];
  const int b = blockIdx.y;
  if (threadIdx.x < G) {
    const float* gp = gts + (size_t)(b * G + threadIdx.x) * 5;
    float x1 = gp[0], y1 = gp[1], x2 = gp[2], y2 = gp[3];
    gbox[threadIdx.x] = make_float4(x1, y1, x2, y2);
    garea[threadIdx.x] = (x2 - x1 + 1.0f) * (y2 - y1 + 1.0f);
  }
  __syncthreads();

  int nn[RPT];
  float ax1[RPT], ay1[RPT], ax2[RPT], ay2[RPT], areaa[RPT];
#pragma unroll
  for (int r = 0; r < RPT; ++r) {
    int n = blockIdx.x * (TPB * RPT) + r * TPB + threadIdx.x;
    nn[r] = n;
    float x1 = 0.f, y1 = 0.f, x2 = 0.f, y2 = 0.f;
    if (n < R) {
      const float* rp = rois + (size_t)(b * R + n) * 5;
      x1 = rp[1]; y1 = rp[2]; x2 = rp[3]; y2 = rp[4];
    } else if (n < N) {
      const float* gp = gts + (size_t)(b * G + (n - R)) * 5;
      x1 = gp[0]; y1 = gp[1]; x2 = gp[2]; y2 = gp[3];
    }
    ax1[r] = x1; ay1[r] = y1; ax2[r] = x2; ay2[r] = y2;
    areaa[r] = (x2 - x1 + 1.0f) * (y2 - y1 + 1.0f);
  }

  float best[RPT];
  int arg[RPT];
#pragma unroll
  for (int r = 0; r < RPT; ++r) { best[r] = 0.0f; arg[r] = 0; }

  for (int g = 0; g < G; ++g) {
    const float4 gb = gbox[g];     // ds_read_b128
    const float gar = garea[g];    // ds_read_b32
#pragma unroll
    for (int r = 0; r < RPT; ++r) {
      float iw = fminf(ax2[r], gb.z) - fmaxf(ax1[r], gb.x) + 1.0f;
      iw = fmaxf(iw, 0.0f);
      float ih = fminf(ay2[r], gb.w) - fmaxf(ay1[r], gb.y) + 1.0f;
      ih = fmaxf(ih, 0.0f);
      float inter = iw * ih;
      float denom = areaa[r] + gar - inter;
      float iou = inter / denom;                 // IEEE, bit-exact
      if (iou > best[r]) { best[r] = iou; arg[r] = g; }  // first-max argmax
    }
  }

  // PRNG keys (wave-uniform parts fold to SALU)
  u32 kb0, kb1, k10, k11, k20, k21;
  batch_key(b, kb0, kb1);
  sub_key(kb0, kb1, 0, k10, k11);
  sub_key(kb0, kb1, 1, k20, k21);

#pragma unroll
  for (int r = 0; r < RPT; ++r) {
    const int n = nn[r];
    if (n >= N) continue;
    gasn[b * N + n] = arg[r];
    const bool fg = best[r] >= 0.5f;
    const bool bg = (best[r] < 0.5f) && (best[r] >= 0.0f);
    u32 u1 = rand_bits(k10, k11, n) >> 9;   // 23-bit mantissa bits = float order
    u32 u2 = rand_bits(k20, k21, n) >> 9;
    fgkey[b * N + n] = fg ? u1 : SENT;
    bgkey[b * N + n] = bg ? u2 : SENT;
    if (fg) {
      atomicAdd(&nfg[b], 1);
      atomicAdd((unsigned int*)&cnt[((size_t)b * 2 + 0) * NBKT + (u1 >> 10)], 1u);
    }
    if (bg) {
      atomicAdd(&nbg[b], 1);
      atomicAdd((unsigned int*)&cnt[((size_t)b * 2 + 1) * NBKT + (u2 >> 10)], 1u);
    }
  }
}

// exclusive scan of cnt[b][set][0..NBKT) in place; copy to cur.
__global__ void k_scan(u32* __restrict__ cnt, u32* __restrict__ cur) {
  constexpr int T = 1024;
  constexpr int PER = NBKT / T;   // 8
  __shared__ u32 sh[T];
  const int b = blockIdx.x, set = blockIdx.y;
  const int tid = threadIdx.x;
  u32* c = cnt + ((size_t)b * 2 + set) * NBKT;
  u32* q = cur + ((size_t)b * 2 + set) * NBKT;
  u32 local[PER];
  u32 tot = 0;
  const int base = tid * PER;
  for (int i = 0; i < PER; ++i) {
    u32 v = c[base + i];
    local[i] = tot;           // exclusive within thread
    tot += v;
  }
  sh[tid] = tot;
  __syncthreads();
  for (int off = 1; off < T; off <<= 1) {
    u32 v = (tid >= off) ? sh[tid - off] : 0u;
    __syncthreads();
    sh[tid] += v;
    __syncthreads();
  }
  const u32 pre = sh[tid] - tot;  // exclusive prefix of this thread
  for (int i = 0; i < PER; ++i) {
    u32 v = pre + local[i];
    c[base + i] = v;
    q[base + i] = v;
  }
}

// scatter composites ((key&1023)<<15 | idx) into bucket ranges
__global__ void k_scatter(const u32* __restrict__ fgkey, const u32* __restrict__ bgkey,
                          u32* __restrict__ cur,
                          u32* __restrict__ slotF, u32* __restrict__ slotB) {
  const int b = blockIdx.y;
  const int n = blockIdx.x * blockDim.x + threadIdx.x;
  if (n >= N) return;
  u32 kf = fgkey[(size_t)b * N + n];
  if (kf != SENT) {
    u32 bkt = kf >> 10;
    u32 pos = atomicAdd((unsigned int*)&cur[((size_t)b * 2 + 0) * NBKT + bkt], 1u);
    slotF[(size_t)b * N + pos] = ((kf & 1023u) << 15) | (u32)n;
  }
  u32 kb = bgkey[(size_t)b * N + n];
  if (kb != SENT) {
    u32 bkt = kb >> 10;
    u32 pos = atomicAdd((unsigned int*)&cur[((size_t)b * 2 + 1) * NBKT + bkt], 1u);
    slotB[(size_t)b * N + pos] = ((kb & 1023u) << 15) | (u32)n;
  }
}

// insertion sort within each bucket; composite order == stable (key, idx)
__global__ void k_bsort(const u32* __restrict__ cnt /*scanned=start*/,
                        const u32* __restrict__ cur /*end*/,
                        u32* __restrict__ slotF, u32* __restrict__ slotB) {
  const int t = blockIdx.x * blockDim.x + threadIdx.x;
  const int total = B * 2 * NBKT;
  if (t >= total) return;
  const int bs = t / NBKT;        // b*2+set
  u32* slot = ((bs & 1) ? slotB : slotF) + (size_t)(bs >> 1) * N;
  const u32 s0 = cnt[t];
  const u32 e = cur[t];
  for (u32 i = s0 + 1; i < e; ++i) {
    u32 v = slot[i];
    int j = (int)i - 1;
    while (j >= (int)s0 && slot[j] > v) { slot[j + 1] = slot[j]; --j; }
    slot[j + 1] = v;
  }
}

__global__ void k_sample(const float* __restrict__ rois, const float* __restrict__ gts,
                         const float* __restrict__ means, const float* __restrict__ stds,
                         const int* __restrict__ nfgA, const int* __restrict__ nbgA,
                         const u32* __restrict__ slotF, const u32* __restrict__ slotB,
                         const int* __restrict__ gasn, float* __restrict__ out) {
#pragma clang fp contract(off)
  const int b = blockIdx.x;
  const int s = threadIdx.x;
  const int nfg = nfgA[b];
  const int nbg = nbgA[b];

  u32 kb0, kb1, k30, k31, k40, k41;
  batch_key(b, kb0, kb1);
  sub_key(kb0, kb1, 2, k30, k31);
  sub_key(kb0, kb1, 3, k40, k41);
  float rf = bits_to_uniform(rand_bits(k30, k31, s));
  float rb = bits_to_uniform(rand_bits(k40, k41, s));

  int n_fg_take = (nbg > 0) ? min(KFG, nfg) : S;
  if (nfg <= 0) n_fg_take = 0;

  int keep;
  if (s < n_fg_take) {
    int fi;
    if (nbg > 0) fi = s;                       // s < n_fg_take <= nfg
    else {
      fi = (int)(rf * (float)nfg);             // f32 mul, trunc
      fi = max(0, min(fi, nfg - 1));
    }
    keep = (int)(slotF[(size_t)b * N + fi] & 0x7FFFu);
  } else {
    if (nbg > 0) {
      int bi = (int)(rb * (float)nbg);
      bi = max(0, min(bi, nbg - 1));
      keep = (int)(slotB[(size_t)b * N + bi] & 0x7FFFu);
    } else {
      keep = 0;  // all-sentinel stable argsort -> identity -> index 0
    }
  }
  keep = max(0, min(keep, N - 1));

  const int ga = gasn[b * N + keep];
  const float* gp = gts + (size_t)(b * G + ga) * 5;
  const bool isfg = s < n_fg_take;
  const float label = isfg ? gp[4] : 0.0f;

  float ax1, ay1, ax2, ay2;
  if (keep < R) {
    const float* rp = rois + (size_t)(b * R + keep) * 5;
    ax1 = rp[1]; ay1 = rp[2]; ax2 = rp[3]; ay2 = rp[4];
  } else {
    const float* g2 = gts + (size_t)(b * G + (keep - R)) * 5;
    ax1 = g2[0]; ay1 = g2[1]; ax2 = g2[2]; ay2 = g2[3];
  }
  const float gx1 = gp[0], gy1 = gp[1], gx2 = gp[2], gy2 = gp[3];

  float ew = ax2 - ax1 + 1.0f, eh = ay2 - ay1 + 1.0f;
  float ecx = ax1 + 0.5f * ew, ecy = ay1 + 0.5f * eh;
  float gw = gx2 - gx1 + 1.0f, gh = gy2 - gy1 + 1.0f;
  float gcx = gx1 + 0.5f * gw, gcy = gy1 + 0.5f * gh;
  float t0 = (gcx - ecx) / ew;
  float t1 = (gcy - ecy) / eh;
  float t2 = logf(gw / ew);
  float t3 = logf(gh / eh);
  const float msk = (label > 0.0f) ? 1.0f : 0.0f;
  t0 = (t0 - means[0]) / stds[0] * msk;
  t1 = (t1 - means[1]) / stds[1] * msk;
  t2 = (t2 - means[2]) / stds[2] * msk;
  t3 = (t3 - means[3]) / stds[3] * msk;

  float* rout = out;                        // [B,S,5]
  float* lout = out + (size_t)B * S * 5;    // [B,S]
  float* tout = lout + (size_t)B * S;       // [B,S,4]
  float* rp2 = rout + (size_t)(b * S + s) * 5;
  rp2[0] = (float)b;
  rp2[1] = ax1; rp2[2] = ay1; rp2[3] = ax2; rp2[4] = ay2;
  lout[b * S + s] = label;
  float* tp = tout + (size_t)(b * S + s) * 4;
  tp[0] = t0; tp[1] = t1; tp[2] = t2; tp[3] = t3;
}

// ---------------- launch ----------------
extern "C" void kernel_launch(void* const* d_in, const int* in_sizes, int n_in,
                              void* d_out, int out_size, void* d_ws, size_t ws_size,
                              hipStream_t stream) {
  const float* rois  = (const float*)d_in[0];
  const float* gts   = (const float*)d_in[1];
  const float* means = (const float*)d_in[2];
  const float* stds  = (const float*)d_in[3];

  char* ws = (char*)d_ws;
  const size_t per = (size_t)B * N;
  const size_t bkts = (size_t)B * 2 * NBKT;
  u32* fgkey = (u32*)ws; ws += per * sizeof(u32);
  u32* bgkey = (u32*)ws; ws += per * sizeof(u32);
  int* gasn  = (int*)ws; ws += per * sizeof(int);
  u32* slotF = (u32*)ws; ws += per * sizeof(u32);
  u32* slotB = (u32*)ws; ws += per * sizeof(u32);
  u32* cnt   = (u32*)ws; ws += bkts * sizeof(u32);   // becomes scanned bases
  u32* cur   = (u32*)ws; ws += bkts * sizeof(u32);   // atomic cursors / ends
  int* nfg   = (int*)ws; ws += B * sizeof(int);
  int* nbg   = (int*)ws; ws += B * sizeof(int);

  const int nb = (N + 255) / 256;
  const int nbA = (N + TPB * RPT - 1) / (TPB * RPT);   // 40
  hipLaunchKernelGGL(k_zero, dim3((int)((bkts + 1023) / 1024)), dim3(1024), 0, stream,
                     cnt, nfg, nbg);
  hipLaunchKernelGGL(k_assign, dim3(nbA, B), dim3(TPB), 0, stream,
                     rois, gts, fgkey, bgkey, gasn, cnt, nfg, nbg);
  hipLaunchKernelGGL(k_scan, dim3(B, 2), dim3(1024), 0, stream, cnt, cur);
  hipLaunchKernelGGL(k_scatter, dim3(nb, B), dim3(256), 0, stream,
                     fgkey, bgkey, cur, slotF, slotB);
  hipLaunchKernelGGL(k_bsort, dim3((B * 2 * NBKT + 255) / 256), dim3(256), 0, stream,
                     cnt, cur, slotF, slotB);
  hipLaunchKernelGGL(k_sample, dim3(B), dim3(S), 0, stream,
                     rois, gts, means, stds, nfg, nbg, slotF, slotB, gasn,
                     (float*)d_out);
}

// Round 4
// 114.771 us; speedup vs baseline: 1.1346x; 1.1346x over previous
//
#include <hip/hip_runtime.h>
#include <stdint.h>

// buildProposalTargetLayer — exact JAX replication (partitionable threefry).
// Pipeline (3 kernels, no pre-zeroing needed):
//   k_assign : quad-per-ROI IoU max/argmax (shfl reduce), masks, uniform keys
//   k_sort   : per-(b,set) fused LDS histogram + scan + scatter + bucket sort,
//              writes nfg/nbg and the rank-count sentinel entry
//   k_sample : per-slot sampling + bbox target encoding -> d_out

typedef uint32_t u32;
typedef uint64_t u64;

constexpr int B    = 16;
constexpr int R    = 20000;
constexpr int G    = 100;
constexpr int N    = R + G;    // 20100
constexpr int S    = 512;
constexpr int KFG  = 128;
constexpr int NBKT = 8192;     // key>>10 buckets (23-bit keys)
constexpr u32 SENT = 0xFFFFFFFFu;
constexpr int TPB  = 256;      // k_assign block size
constexpr int ST   = 1024;     // k_sort block size
constexpr int GPL  = G / 4;    // GTs per lane in a quad (25)

// ---------------- threefry2x32 (20 rounds) ----------------
__device__ __forceinline__ void tf2x32(u32 k0, u32 k1, u32 x0, u32 x1,
                                       u32& o0, u32& o1) {
  u32 ks2 = k0 ^ k1 ^ 0x1BD11BDAu;
#define TFR(r) { x0 += x1; x1 = (x1 << (r)) | (x1 >> (32 - (r))); x1 ^= x0; }
  x0 += k0; x1 += k1;
  TFR(13) TFR(15) TFR(26) TFR(6)
  x0 += k1;  x1 += ks2 + 1u;
  TFR(17) TFR(29) TFR(16) TFR(24)
  x0 += ks2; x1 += k0 + 2u;
  TFR(13) TFR(15) TFR(26) TFR(6)
  x0 += k0;  x1 += k1 + 3u;
  TFR(17) TFR(29) TFR(16) TFR(24)
  x0 += k1;  x1 += ks2 + 4u;
  TFR(13) TFR(15) TFR(26) TFR(6)
  x0 += ks2; x1 += k0 + 5u;
#undef TFR
  o0 = x0; o1 = x1;
}

__device__ __forceinline__ void batch_key(int b, u32& kb0, u32& kb1) {
  tf2x32(0u, 42u, 0u, (u32)b, kb0, kb1);
}
__device__ __forceinline__ void sub_key(u32 kb0, u32 kb1, int j, u32& k0, u32& k1) {
  tf2x32(kb0, kb1, 0u, (u32)j, k0, k1);
}
__device__ __forceinline__ u32 rand_bits(u32 k0, u32 k1, int i) {
  u32 b0, b1;
  tf2x32(k0, k1, 0u, (u32)i, b0, b1);
  return b0 ^ b1;
}
__device__ __forceinline__ float bits_to_uniform(u32 bits) {
  return __uint_as_float((bits >> 9) | 0x3f800000u) - 1.0f;
}

// ---------------- k_assign: quad (4 threads) per ROI ----------------
__global__ __launch_bounds__(TPB) void
k_assign(const float* __restrict__ rois, const float* __restrict__ gts,
         u32* __restrict__ fgkey, u32* __restrict__ bgkey,
         int* __restrict__ gasn) {
#pragma clang fp contract(off)
  __shared__ float4 gbox[G];
  __shared__ float garea[G];
  const int b = blockIdx.y;
  if (threadIdx.x < G) {
    const float* gp = gts + (size_t)(b * G + threadIdx.x) * 5;
    float x1 = gp[0], y1 = gp[1], x2 = gp[2], y2 = gp[3];
    gbox[threadIdx.x] = make_float4(x1, y1, x2, y2);
    garea[threadIdx.x] = (x2 - x1 + 1.0f) * (y2 - y1 + 1.0f);
  }
  __syncthreads();

  const int t = blockIdx.x * TPB + threadIdx.x;
  const int n = t >> 2;           // ROI index
  const int r = t & 3;            // lane-in-quad -> g chunk
  if (n >= N) return;             // whole quad exits together

  float ax1, ay1, ax2, ay2;
  if (n < R) {
    const float* rp = rois + (size_t)(b * R + n) * 5;
    ax1 = rp[1]; ay1 = rp[2]; ax2 = rp[3]; ay2 = rp[4];
  } else {
    const float* gp = gts + (size_t)(b * G + (n - R)) * 5;
    ax1 = gp[0]; ay1 = gp[1]; ax2 = gp[2]; ay2 = gp[3];
  }
  const float areaa = (ax2 - ax1 + 1.0f) * (ay2 - ay1 + 1.0f);

  const int g0 = r * GPL;
  float best = 0.0f;              // IoU >= 0; matches argmax-first with all-zero
  int arg = g0;
#pragma unroll 5
  for (int gi = 0; gi < GPL; ++gi) {
    const int g = g0 + gi;
    const float4 gb = gbox[g];
    const float gar = garea[g];
    float iw = fminf(ax2, gb.z) - fmaxf(ax1, gb.x) + 1.0f;
    iw = fmaxf(iw, 0.0f);
    float ih = fminf(ay2, gb.w) - fmaxf(ay1, gb.y) + 1.0f;
    ih = fmaxf(ih, 0.0f);
    float inter = iw * ih;
    float denom = (areaa + gar) - inter;
    float iou = inter / denom;                 // IEEE, bit-exact
    if (iou > best) { best = iou; arg = g; }   // first-max within chunk
  }

  // quad argmax-reduce: larger value wins; tie -> smaller g (first occurrence)
#pragma unroll
  for (int m = 1; m <= 2; m <<= 1) {
    float ob = __shfl_xor(best, m);
    int og = __shfl_xor(arg, m);
    if (ob > best || (ob == best && og < arg)) { best = ob; arg = og; }
  }

  if (r == 0) {
    gasn[b * N + n] = arg;
    const bool fg = best >= 0.5f;
    const bool bg = (best < 0.5f) && (best >= 0.0f);
    u32 kb0, kb1, k10, k11, k20, k21;
    batch_key(b, kb0, kb1);            // wave-uniform -> SALU
    sub_key(kb0, kb1, 0, k10, k11);
    sub_key(kb0, kb1, 1, k20, k21);
    u32 u1 = rand_bits(k10, k11, n) >> 9;   // 23-bit mantissa bits = float order
    u32 u2 = rand_bits(k20, k21, n) >> 9;
    fgkey[(size_t)b * N + n] = fg ? u1 : SENT;
    bgkey[(size_t)b * N + n] = bg ? u2 : SENT;
  }
}

// ---------------- k_sort: fused histogram + scan + scatter + bucket sort ----
__global__ __launch_bounds__(ST) void
k_sort(const u32* __restrict__ fgkey, const u32* __restrict__ bgkey,
       u32* __restrict__ slotF, u32* __restrict__ slotB,
       int* __restrict__ nfg, int* __restrict__ nbg) {
  constexpr int PER = NBKT / ST;   // 8
  __shared__ u32 hist[NBKT];       // 32 KB
  __shared__ u32 sh[ST];           // 4 KB
  __shared__ u32 minsent;
  const int b = blockIdx.x, set = blockIdx.y;
  const u32* key = (set ? bgkey : fgkey) + (size_t)b * N;
  u32* slot = (set ? slotB : slotF) + (size_t)b * N;
  const int tid = threadIdx.x;

  for (int i = tid; i < NBKT; i += ST) hist[i] = 0;
  if (tid == 0) minsent = 0x7FFFFFFFu;
  __syncthreads();

  // pass 1: histogram + smallest non-candidate index
  for (int i = tid; i < N; i += ST) {
    u32 k = key[i];
    if (k != SENT) atomicAdd(&hist[k >> 10], 1u);
    else atomicMin(&minsent, (u32)i);
  }
  __syncthreads();

  // exclusive scan of hist in place
  u32 local[PER];
  u32 tot = 0;
  const int base = tid * PER;
#pragma unroll
  for (int i = 0; i < PER; ++i) { u32 v = hist[base + i]; local[i] = tot; tot += v; }
  sh[tid] = tot;
  __syncthreads();
  for (int off = 1; off < ST; off <<= 1) {
    u32 v = (tid >= off) ? sh[tid - off] : 0u;
    __syncthreads();
    sh[tid] += v;
    __syncthreads();
  }
  const u32 pre = sh[tid] - tot;
  const u32 total = sh[ST - 1];
#pragma unroll
  for (int i = 0; i < PER; ++i) hist[base + i] = pre + local[i];
  __syncthreads();

  // pass 2: scatter composites ((key&1023)<<15 | idx) via LDS cursors
  for (int i = tid; i < N; i += ST) {
    u32 k = key[i];
    if (k != SENT) {
      u32 pos = atomicAdd(&hist[k >> 10], 1u);
      slot[pos] = ((k & 1023u) << 15) | (u32)i;
    }
  }
  __syncthreads();   // hist now holds bucket ENDs; starts = prev bucket's end

  if (tid == 0) {
    // rank == total in JAX's full argsort = smallest non-candidate index.
    if (total < (u32)N) slot[total] = (minsent == 0x7FFFFFFFu) ? 0u : minsent;
    if (set) nbg[b] = (int)total; else nfg[b] = (int)total;
  }

  // pass 3: insertion sort per bucket (avg ~2.5 elems); composite asc == (key,idx)
  for (int bu = tid; bu < NBKT; bu += ST) {
    u32 e = hist[bu];
    u32 s0 = (bu == 0) ? 0u : hist[bu - 1];
    for (u32 i = s0 + 1; i < e; ++i) {
      u32 v = slot[i];
      int j = (int)i - 1;
      while (j >= (int)s0 && slot[j] > v) { slot[j + 1] = slot[j]; --j; }
      slot[j + 1] = v;
    }
  }
}

// ---------------- k_sample ----------------
__global__ void k_sample(const float* __restrict__ rois, const float* __restrict__ gts,
                         const float* __restrict__ means, const float* __restrict__ stds,
                         const int* __restrict__ nfgA, const int* __restrict__ nbgA,
                         const u32* __restrict__ slotF, const u32* __restrict__ slotB,
                         const int* __restrict__ gasn, float* __restrict__ out) {
#pragma clang fp contract(off)
  const int b = blockIdx.x;
  const int s = threadIdx.x;
  const int nfg = nfgA[b];
  const int nbg = nbgA[b];

  u32 kb0, kb1, k30, k31, k40, k41;
  batch_key(b, kb0, kb1);
  sub_key(kb0, kb1, 2, k30, k31);
  sub_key(kb0, kb1, 3, k40, k41);
  float rf = bits_to_uniform(rand_bits(k30, k31, s));
  float rb = bits_to_uniform(rand_bits(k40, k41, s));

  int n_fg_take = (nbg > 0) ? min(KFG, nfg) : S;
  if (nfg <= 0) n_fg_take = 0;

  int keep;
  if (s < n_fg_take) {
    int fi;
    if (nbg > 0) fi = s;                       // s < n_fg_take <= nfg
    else {
      fi = (int)(rf * (float)nfg);             // f32 mul, trunc
      fi = max(0, min(fi, nfg));               // rank nfg = sentinel entry (exact)
    }
    keep = (int)(slotF[(size_t)b * N + fi] & 0x7FFFu);
  } else {
    if (nbg > 0) {
      int bi = (int)(rb * (float)nbg);
      bi = max(0, min(bi, nbg));               // rank nbg = sentinel entry (exact)
      keep = (int)(slotB[(size_t)b * N + bi] & 0x7FFFu);
    } else {
      keep = 0;  // all-sentinel stable argsort -> identity -> index 0
    }
  }
  keep = max(0, min(keep, N - 1));

  const int ga = gasn[b * N + keep];
  const float* gp = gts + (size_t)(b * G + ga) * 5;
  const bool isfg = s < n_fg_take;
  const float label = isfg ? gp[4] : 0.0f;

  float ax1, ay1, ax2, ay2;
  if (keep < R) {
    const float* rp = rois + (size_t)(b * R + keep) * 5;
    ax1 = rp[1]; ay1 = rp[2]; ax2 = rp[3]; ay2 = rp[4];
  } else {
    const float* g2 = gts + (size_t)(b * G + (keep - R)) * 5;
    ax1 = g2[0]; ay1 = g2[1]; ax2 = g2[2]; ay2 = g2[3];
  }
  const float gx1 = gp[0], gy1 = gp[1], gx2 = gp[2], gy2 = gp[3];

  float ew = ax2 - ax1 + 1.0f, eh = ay2 - ay1 + 1.0f;
  float ecx = ax1 + 0.5f * ew, ecy = ay1 + 0.5f * eh;
  float gw = gx2 - gx1 + 1.0f, gh = gy2 - gy1 + 1.0f;
  float gcx = gx1 + 0.5f * gw, gcy = gy1 + 0.5f * gh;
  float t0 = (gcx - ecx) / ew;
  float t1 = (gcy - ecy) / eh;
  float t2 = logf(gw / ew);
  float t3 = logf(gh / eh);
  const float msk = (label > 0.0f) ? 1.0f : 0.0f;
  t0 = (t0 - means[0]) / stds[0] * msk;
  t1 = (t1 - means[1]) / stds[1] * msk;
  t2 = (t2 - means[2]) / stds[2] * msk;
  t3 = (t3 - means[3]) / stds[3] * msk;

  float* rout = out;                        // [B,S,5]
  float* lout = out + (size_t)B * S * 5;    // [B,S]
  float* tout = lout + (size_t)B * S;       // [B,S,4]
  float* rp2 = rout + (size_t)(b * S + s) * 5;
  rp2[0] = (float)b;
  rp2[1] = ax1; rp2[2] = ay1; rp2[3] = ax2; rp2[4] = ay2;
  lout[b * S + s] = label;
  float* tp = tout + (size_t)(b * S + s) * 4;
  tp[0] = t0; tp[1] = t1; tp[2] = t2; tp[3] = t3;
}

// ---------------- launch ----------------
extern "C" void kernel_launch(void* const* d_in, const int* in_sizes, int n_in,
                              void* d_out, int out_size, void* d_ws, size_t ws_size,
                              hipStream_t stream) {
  const float* rois  = (const float*)d_in[0];
  const float* gts   = (const float*)d_in[1];
  const float* means = (const float*)d_in[2];
  const float* stds  = (const float*)d_in[3];

  char* ws = (char*)d_ws;
  const size_t per = (size_t)B * N;
  u32* fgkey = (u32*)ws; ws += per * sizeof(u32);
  u32* bgkey = (u32*)ws; ws += per * sizeof(u32);
  int* gasn  = (int*)ws; ws += per * sizeof(int);
  u32* slotF = (u32*)ws; ws += per * sizeof(u32);
  u32* slotB = (u32*)ws; ws += per * sizeof(u32);
  int* nfg   = (int*)ws; ws += B * sizeof(int);
  int* nbg   = (int*)ws; ws += B * sizeof(int);

  const int nbA = (N * 4 + TPB - 1) / TPB;   // 315 blocks/batch, quad per ROI
  hipLaunchKernelGGL(k_assign, dim3(nbA, B), dim3(TPB), 0, stream,
                     rois, gts, fgkey, bgkey, gasn);
  hipLaunchKernelGGL(k_sort, dim3(B, 2), dim3(ST), 0, stream,
                     fgkey, bgkey, slotF, slotB, nfg, nbg);
  hipLaunchKernelGGL(k_sample, dim3(B), dim3(S), 0, stream,
                     rois, gts, means, stds, nfg, nbg, slotF, slotB, gasn,
                     (float*)d_out);
}